// Round 10
// baseline (118.435 us; speedup 1.0000x reference)
//
#include <hip/hip_runtime.h>

// Problem constants (fixed by the reference)
#define NN 8192
#define EE 262144
#define CC 64
#define STRIDE 96   // bucket slots/row; Poisson(32) max ~66, P(>96) ~ 1e-19

typedef unsigned long long u64;

// ---- 1. zero per-row counters
__global__ void k_zero(int* __restrict__ cnt) {
    int i = blockIdx.x * blockDim.x + threadIdx.x;
    if (i < NN) cnt[i] = 0;
}

// ---- 2. bucket fill: slot = atomicAdd(cnt[r]); one u64 store per edge.
//         hi32 = (e<<13)|col  (max packed == last write, per col), lo32 = ew
__global__ void k_fill(const int* __restrict__ ei, const float* __restrict__ ew,
                       int* __restrict__ cnt, u64* __restrict__ ecw) {
    int e = blockIdx.x * blockDim.x + threadIdx.x;
    if (e >= EE) return;
    int r = ei[e];
    int c = ei[EE + e];
    int pos = atomicAdd(&cnt[r], 1);
    if (pos < STRIDE) {
        u64 v = ((u64)(((unsigned)e << 13) | (unsigned)c) << 32)
              | (u64)__float_as_uint(ew[e]);
        ecw[r * STRIDE + pos] = v;
    }
}

// ---- 3. per-row dedup in LDS (last-write-wins) + weighted degree + dinv.
//         Rewrites slot as (col<<32)|w_final (losers w=0). One wave per row.
__global__ __launch_bounds__(256) void k_dedup(
        const int* __restrict__ cnt, u64* __restrict__ ecw,
        const float* __restrict__ adw, float* __restrict__ dinv) {
    __shared__ u64 se[4][STRIDE];
    int tid = threadIdx.x;
    int lane = tid & 63;
    int rloc = tid >> 6;
    int row = blockIdx.x * 4 + rloc;
    int b = row * STRIDE;
    int k = cnt[row];
    if (k > STRIDE) k = STRIDE;
    for (int i = lane; i < k; i += 64) se[rloc][i] = ecw[b + i];
    __syncthreads();

    float sig = 1.0f / (1.0f + expf(-adw[0]));
    float degsum = 0.0f;
    for (int i = lane; i < k; i += 64) {
        u64 vi = se[rloc][i];
        unsigned pi = (unsigned)(vi >> 32);
        unsigned ci = pi & 0x1FFFu;
        bool win = true;
        for (int j = 0; j < k; ++j) {          // LDS same-address broadcasts
            unsigned pj = (unsigned)(se[rloc][j] >> 32);
            win = win && !(((pj ^ pi) & 0x1FFFu) == 0u && pj > pi);
        }
        float wi = win ? __uint_as_float((unsigned)vi) * sig : 0.0f;
        ecw[b + i] = ((u64)ci << 32) | (u64)__float_as_uint(wi);
        degsum += wi;
    }
    for (int off = 32; off > 0; off >>= 1) degsum += __shfl_down(degsum, off);
    if (lane == 0) dinv[row] = 1.0f / sqrtf(1.0f + degsum);  // +1: I diagonal
}

// ---- register-resident gather core. Each lane owns slots {lane, lane+64}
//      (one coalesced 512B wave-load of ecw), folds dinv[col] once; the gather
//      loop broadcasts (col,w) via shfl so addresses are pure register ALU.
//      Trip count is WAVE-UNIFORM ((k+3)>>2 for every lane) so every __shfl
//      executes with all 64 lanes active (R7/R8 bug: per-lane loop exit masked
//      off shfl source lanes in the tail iteration -> corrupted edge).
//      For j in [k, 4*trips): source lane j holds w=0 (guarded preload), so
//      those iterations contribute exactly 0.
static __device__ __forceinline__ float4 reg_gather(
        const u64* __restrict__ ecw, const float* __restrict__ dinv,
        const float* __restrict__ src, int b, int k, int lane, int sub, int ch) {
    u64 v0 = (lane < k)      ? ecw[b + lane]      : 0ull;
    u64 v1 = (lane + 64 < k) ? ecw[b + 64 + lane] : 0ull;
    int col0 = (int)(v0 >> 32);
    int col1 = (int)(v1 >> 32);
    float w0 = __uint_as_float((unsigned)v0) * dinv[col0];   // 0 for empty slots
    float w1 = __uint_as_float((unsigned)v1) * dinv[col1];

    float4 acc = {0.f, 0.f, 0.f, 0.f};
    int trips = (k + 3) >> 2;            // wave-uniform
#pragma unroll 4
    for (int i = 0; i < trips; ++i) {
        int j = (i << 2) + sub;          // j < 64 test is uniform per i
        int cj; float wj;
        if (j < 64) { cj = __shfl(col0, j);      wj = __shfl(w0, j); }
        else        { cj = __shfl(col1, j - 64); wj = __shfl(w1, j - 64); }
        float4 uv = *(const float4*)(src + (cj << 6) + ch);
        acc.x = fmaf(wj, uv.x, acc.x);
        acc.y = fmaf(wj, uv.y, acc.y);
        acc.z = fmaf(wj, uv.z, acc.z);
        acc.w = fmaf(wj, uv.w, acc.w);
    }
    acc.x += __shfl_xor(acc.x, 16); acc.x += __shfl_xor(acc.x, 32);
    acc.y += __shfl_xor(acc.y, 16); acc.y += __shfl_xor(acc.y, 32);
    acc.z += __shfl_xor(acc.z, 16); acc.z += __shfl_xor(acc.z, 32);
    acc.w += __shfl_xor(acc.w, 16); acc.w += __shfl_xor(acc.w, 32);
    return acc;
}

// ---- 4. SpMV1 + combine: tx1 = x - d*acc - d^2*x   (one wave per row)
__global__ __launch_bounds__(256) void k_spmv1(
        const int* __restrict__ cnt, const u64* __restrict__ ecw,
        const float* __restrict__ dinv, const float* __restrict__ x,
        float* __restrict__ tx1) {
    int tid = threadIdx.x;
    int lane = tid & 63;
    int rloc = tid >> 6;
    int row = blockIdx.x * 4 + rloc;
    int b = row * STRIDE;
    int k = cnt[row];
    if (k > STRIDE) k = STRIDE;
    int sub = lane >> 4;
    int ch = (lane & 15) << 2;
    float4 acc = reg_gather(ecw, dinv, x, b, k, lane, sub, ch);
    if (sub == 0) {
        float d = dinv[row];
        float dd = d * d;
        int idx = (row << 6) + ch;
        float4 xv = *(const float4*)(x + idx);
        float4 t1;
        t1.x = xv.x - d * acc.x - dd * xv.x;
        t1.y = xv.y - d * acc.y - dd * xv.y;
        t1.z = xv.z - d * acc.z - dd * xv.z;
        t1.w = xv.w - d * acc.w - dd * xv.w;
        *(float4*)(tx1 + idx) = t1;
    }
}

// ---- 5. SpMV2 + combine2 + fused epilogue GEMM
//         tx2 = 2*(tx1 - d*acc - d^2*tx1) - x ; out = x@W0+tx1@W1+tx2@W2+bias
__global__ __launch_bounds__(256) void k_spmv2out(
        const int* __restrict__ cnt, const u64* __restrict__ ecw,
        const float* __restrict__ dinv, const float* __restrict__ x,
        const float* __restrict__ tx1, const float* __restrict__ W,
        const float* __restrict__ bias, float* __restrict__ out) {
    __shared__ float xs[4][CC], t1s[4][CC], t2s[4][CC];
    int tid = threadIdx.x;
    int lane = tid & 63;
    int rloc = tid >> 6;
    int row = blockIdx.x * 4 + rloc;
    int b = row * STRIDE;
    int k = cnt[row];
    if (k > STRIDE) k = STRIDE;
    int sub = lane >> 4;
    int ch = (lane & 15) << 2;
    float4 acc = reg_gather(ecw, dinv, tx1, b, k, lane, sub, ch);
    if (sub == 0) {
        float d = dinv[row];
        float dd = d * d;
        int idx = (row << 6) + ch;
        float4 xv = *(const float4*)(x + idx);
        float4 t1v = *(const float4*)(tx1 + idx);
        float4 t2;
        t2.x = 2.0f * (t1v.x - d * acc.x - dd * t1v.x) - xv.x;
        t2.y = 2.0f * (t1v.y - d * acc.y - dd * t1v.y) - xv.y;
        t2.z = 2.0f * (t1v.z - d * acc.z - dd * t1v.z) - xv.z;
        t2.w = 2.0f * (t1v.w - d * acc.w - dd * t1v.w) - xv.w;
        *(float4*)&xs[rloc][ch]  = xv;
        *(float4*)&t1s[rloc][ch] = t1v;
        *(float4*)&t2s[rloc][ch] = t2;
    }
    __syncthreads();

    // 3 independent accumulator chains (fp32 can't be reassociated by the
    // compiler) -> dependency depth 64 FMA instead of 192.
    int c = lane;
    const float* W0 = W;
    const float* W1 = W + CC * CC;
    const float* W2 = W + 2 * CC * CC;
    float o0 = bias[c], o1 = 0.0f, o2 = 0.0f;
#pragma unroll 16
    for (int kk = 0; kk < CC; ++kk) {
        o0 = fmaf(xs[rloc][kk],  W0[(kk << 6) + c], o0);
        o1 = fmaf(t1s[rloc][kk], W1[(kk << 6) + c], o1);
        o2 = fmaf(t2s[rloc][kk], W2[(kk << 6) + c], o2);
    }
    out[(row << 6) + c] = o0 + o1 + o2;
}

extern "C" void kernel_launch(void* const* d_in, const int* in_sizes, int n_in,
                              void* d_out, int out_size, void* d_ws, size_t ws_size,
                              hipStream_t stream) {
    const float* x    = (const float*)d_in[0];
    const int*   ei   = (const int*)d_in[1];     // int32
    const float* ew   = (const float*)d_in[2];
    const float* W    = (const float*)d_in[3];   // (3,64,64)
    const float* adw  = (const float*)d_in[4];
    const float* bias = (const float*)d_in[5];
    float*       out  = (float*)d_out;

    // workspace (~8.1 MB)
    char* p = (char*)d_ws;
    auto take = [&](size_t bytes) {
        char* q = p;
        p += (bytes + 255) & ~(size_t)255;
        return q;
    };
    int*   cnt  = (int*)take(NN * sizeof(int));                  // 32 KB
    u64*   ecw  = (u64*)take((size_t)NN * STRIDE * sizeof(u64)); // 6 MB
    float* dinv = (float*)take(NN * sizeof(float));              // 32 KB
    float* tx1  = (float*)take(NN * CC * sizeof(float));         // 2 MB

    const int B = 256;
    hipLaunchKernelGGL(k_zero,     dim3(NN / B), dim3(B), 0, stream, cnt);
    hipLaunchKernelGGL(k_fill,     dim3(EE / B), dim3(B), 0, stream, ei, ew, cnt, ecw);
    hipLaunchKernelGGL(k_dedup,    dim3(NN / 4), dim3(B), 0, stream, cnt, ecw, adw, dinv);
    hipLaunchKernelGGL(k_spmv1,    dim3(NN / 4), dim3(B), 0, stream, cnt, ecw, dinv, x, tx1);
    hipLaunchKernelGGL(k_spmv2out, dim3(NN / 4), dim3(B), 0, stream, cnt, ecw, dinv, x, tx1, W, bias, out);
}